// Round 1
// baseline (2002.405 us; speedup 1.0000x reference)
//
#include <hip/hip_runtime.h>
#include <hip/hip_bf16.h>

// ---------------- common helpers ----------------
typedef unsigned short u16;
typedef __attribute__((ext_vector_type(8))) short bf16x8;
typedef __attribute__((ext_vector_type(4))) float floatx4;

__device__ __forceinline__ u16 f2b(float f) {
    union { float f; unsigned int u; } a; a.f = f;
    unsigned int u = a.u;
    // round-to-nearest-even bf16
    unsigned int r = (u + 0x7fffu + ((u >> 16) & 1u)) >> 16;
    return (u16)r;
}

// ---------------- LayerNorm (ddof=1), writes fp32 + bf16 ----------------
// one block per row of 1024; 256 threads, float4 per thread
__global__ __launch_bounds__(256) void k_ln(const float* __restrict__ x,
                                            const float* __restrict__ g,
                                            const float* __restrict__ be,
                                            float* __restrict__ yf,
                                            u16* __restrict__ yb) {
    const int row = blockIdx.x;
    const int t = threadIdx.x;
    const float4 xv = ((const float4*)(x + (size_t)row * 1024))[t];
    float s  = xv.x + xv.y + xv.z + xv.w;
    float ss = xv.x * xv.x + xv.y * xv.y + xv.z * xv.z + xv.w * xv.w;
    for (int m = 1; m < 64; m <<= 1) {
        s  += __shfl_xor(s, m);
        ss += __shfl_xor(ss, m);
    }
    __shared__ float sm[8];
    const int wave = t >> 6, lane = t & 63;
    if (lane == 0) { sm[wave] = s; sm[4 + wave] = ss; }
    __syncthreads();
    s  = sm[0] + sm[1] + sm[2] + sm[3];
    ss = sm[4] + sm[5] + sm[6] + sm[7];
    const float mean = s * (1.0f / 1024.0f);
    const float var  = (ss - 1024.0f * mean * mean) * (1.0f / 1023.0f); // ddof=1
    const float rstd = rsqrtf(var + 1e-5f);
    const float4 gv = ((const float4*)g)[t];
    const float4 bv = ((const float4*)be)[t];
    float4 y;
    y.x = (xv.x - mean) * rstd * gv.x + bv.x;
    y.y = (xv.y - mean) * rstd * gv.y + bv.y;
    y.z = (xv.z - mean) * rstd * gv.z + bv.z;
    y.w = (xv.w - mean) * rstd * gv.w + bv.w;
    ((float4*)(yf + (size_t)row * 1024))[t] = y;
    uint2 pk;
    pk.x = (unsigned int)f2b(y.x) | ((unsigned int)f2b(y.y) << 16);
    pk.y = (unsigned int)f2b(y.z) | ((unsigned int)f2b(y.w) << 16);
    *(uint2*)(yb + (size_t)row * 1024 + t * 4) = pk;
}

// ---------------- weight transpose + convert: W(KxN) fp32 -> Wt(NxK) bf16 ----------------
__global__ __launch_bounds__(256) void k_tconv(const float* __restrict__ W,
                                               u16* __restrict__ Wt,
                                               int K, int N) {
    __shared__ float tile[32][33];
    const int n0 = blockIdx.x * 32, k0 = blockIdx.y * 32;
    const int tx = threadIdx.x, ty = threadIdx.y; // 32 x 8
    for (int i = 0; i < 4; i++) {
        const int kr = ty + i * 8;
        tile[kr][tx] = W[(size_t)(k0 + kr) * N + n0 + tx];
    }
    __syncthreads();
    for (int i = 0; i < 4; i++) {
        const int nr = ty + i * 8;
        Wt[(size_t)(n0 + nr) * K + k0 + tx] = f2b(tile[tx][nr]);
    }
}

// ---------------- bf16 MFMA GEMM: C = A(MxK) @ Bt(NxK)^T + bias ----------------
// 128x128 tile, BK=32, 256 threads (4 waves, each 64x64 = 4x4 frags of 16x16x32)
template <bool GELU, bool RESID, bool WF32, bool WBF16>
__global__ __launch_bounds__(256) void k_gemm(const u16* __restrict__ A,
                                              const u16* __restrict__ Bt,
                                              const float* __restrict__ bias,
                                              const float* __restrict__ resid,
                                              float* __restrict__ outF,
                                              u16* __restrict__ outB,
                                              int M, int N, int K) {
    __shared__ u16 As[128 * 32];
    __shared__ u16 Bs[128 * 32];
    const int t = threadIdx.x;
    const int m0 = blockIdx.y * 128, n0 = blockIdx.x * 128;
    const int lane = t & 63, wave = t >> 6;
    const int wm = (wave >> 1) * 64, wn = (wave & 1) * 64;
    const int r16 = lane & 15, quad = lane >> 4;

    floatx4 acc[4][4];
    const floatx4 zero = {0.0f, 0.0f, 0.0f, 0.0f};
    for (int i = 0; i < 4; i++)
        for (int j = 0; j < 4; j++) acc[i][j] = zero;

    // staging: tile = 128 rows x 64B = 512 x 16B chunks; 2 chunks/thread
    const int c0 = t, c1 = t + 256;
    const int r0 = c0 >> 2, f0 = c0 & 3;
    const int r1 = c1 >> 2, f1 = c1 & 3;

    for (int kk = 0; kk < K; kk += 32) {
        const uint4 va0 = *(const uint4*)(A  + (size_t)(m0 + r0) * K + kk + f0 * 8);
        const uint4 vb0 = *(const uint4*)(Bt + (size_t)(n0 + r0) * K + kk + f0 * 8);
        const uint4 va1 = *(const uint4*)(A  + (size_t)(m0 + r1) * K + kk + f1 * 8);
        const uint4 vb1 = *(const uint4*)(Bt + (size_t)(n0 + r1) * K + kk + f1 * 8);
        *(uint4*)(As + r0 * 32 + f0 * 8) = va0;
        *(uint4*)(Bs + r0 * 32 + f0 * 8) = vb0;
        *(uint4*)(As + r1 * 32 + f1 * 8) = va1;
        *(uint4*)(Bs + r1 * 32 + f1 * 8) = vb1;
        __syncthreads();

        bf16x8 af[4], bfr[4];
        for (int i = 0; i < 4; i++)
            af[i] = *(const bf16x8*)(As + (wm + i * 16 + r16) * 32 + quad * 8);
        for (int i = 0; i < 4; i++)
            bfr[i] = *(const bf16x8*)(Bs + (wn + i * 16 + r16) * 32 + quad * 8);
        for (int mi = 0; mi < 4; mi++)
            for (int ni = 0; ni < 4; ni++)
                acc[mi][ni] = __builtin_amdgcn_mfma_f32_16x16x32_bf16(af[mi], bfr[ni], acc[mi][ni], 0, 0, 0);
        __syncthreads();
    }

    // epilogue: C/D layout col = lane&15, row = quad*4 + reg
    for (int mi = 0; mi < 4; mi++)
        for (int ni = 0; ni < 4; ni++) {
            const int gcol = n0 + wn + ni * 16 + r16;
            const float bv = bias[gcol];
            for (int r = 0; r < 4; r++) {
                const int grow = m0 + wm + mi * 16 + quad * 4 + r;
                float v = acc[mi][ni][r] + bv;
                if (GELU) v = 0.5f * v * (1.0f + erff(v * 0.70710678118654752f));
                const size_t o = (size_t)grow * N + gcol;
                if (RESID) v += resid[o];
                if (WF32) outF[o] = v;
                if (WBF16) outB[o] = f2b(v);
            }
        }
}

// ---------------- FP32 flash attention ----------------
// grid: B*H*(T/64) blocks of 256 threads; each block: one (b,h), 64 q rows.
// thread (ty,tx) (ty=t/16, tx=t%15) owns 4x4 micro-tiles; HD=64, T=1024, D=1024
__global__ __launch_bounds__(256) void k_attn(const float* __restrict__ q,
                                              const float* __restrict__ k,
                                              const float* __restrict__ v,
                                              u16* __restrict__ ctx) {
    __shared__ float Qs[64][68];
    __shared__ float Ks[64][68];
    __shared__ float Ps[64][68];
    __shared__ float Vs[64][64];
    const int t = threadIdx.x;
    const int tx = t & 15, ty = t >> 4;
    const int bx = blockIdx.x;
    const int qt = bx & 15, hh = (bx >> 4) & 15, bb = bx >> 8;
    const size_t base = ((size_t)bb * 1024) * 1024 + hh * 64;
    const int q0 = qt * 64;

    // stage Q (scaled by HD^-0.5 = 0.125)
    for (int i = 0; i < 4; i++) {
        const int c = i * 256 + t;
        const int row = c >> 4, c4 = c & 15;
        float4 f = *(const float4*)(q + base + (size_t)(q0 + row) * 1024 + c4 * 4);
        f.x *= 0.125f; f.y *= 0.125f; f.z *= 0.125f; f.w *= 0.125f;
        *(float4*)&Qs[row][c4 * 4] = f;
    }

    float m_i[4], l_i[4], o_[4][4];
    for (int i = 0; i < 4; i++) {
        m_i[i] = -INFINITY; l_i[i] = 0.0f;
        for (int j = 0; j < 4; j++) o_[i][j] = 0.0f;
    }

    for (int st = 0; st < 16; st++) {
        __syncthreads(); // prev PV done before restage
        const int s0 = st * 64;
        for (int i = 0; i < 4; i++) {
            const int c = i * 256 + t;
            const int row = c >> 4, c4 = c & 15;
            *(float4*)&Ks[row][c4 * 4] = *(const float4*)(k + base + (size_t)(s0 + row) * 1024 + c4 * 4);
            *(float4*)&Vs[row][c4 * 4] = *(const float4*)(v + base + (size_t)(s0 + row) * 1024 + c4 * 4);
        }
        __syncthreads();

        // S = Q K^T : rows ty*4+i, cols tx*4+j
        float s_[4][4] = {{0}};
        for (int d4 = 0; d4 < 16; d4++) {
            float4 q4[4], k4[4];
            for (int i = 0; i < 4; i++) q4[i] = *(float4*)&Qs[ty * 4 + i][d4 * 4];
            for (int j = 0; j < 4; j++) k4[j] = *(float4*)&Ks[tx * 4 + j][d4 * 4];
            for (int i = 0; i < 4; i++)
                for (int j = 0; j < 4; j++)
                    s_[i][j] += q4[i].x * k4[j].x + q4[i].y * k4[j].y +
                                q4[i].z * k4[j].z + q4[i].w * k4[j].w;
        }

        // online softmax per row (16 lanes share a row: same ty)
        for (int i = 0; i < 4; i++) {
            float mx = fmaxf(fmaxf(s_[i][0], s_[i][1]), fmaxf(s_[i][2], s_[i][3]));
            for (int m = 1; m < 16; m <<= 1) mx = fmaxf(mx, __shfl_xor(mx, m));
            const float mn = fmaxf(m_i[i], mx);
            const float alpha = __expf(m_i[i] - mn);
            float ps = 0.0f;
            for (int j = 0; j < 4; j++) { s_[i][j] = __expf(s_[i][j] - mn); ps += s_[i][j]; }
            for (int m = 1; m < 16; m <<= 1) ps += __shfl_xor(ps, m);
            l_i[i] = l_i[i] * alpha + ps;
            m_i[i] = mn;
            for (int j = 0; j < 4; j++) o_[i][j] *= alpha;
            *(float4*)&Ps[ty * 4 + i][tx * 4] = make_float4(s_[i][0], s_[i][1], s_[i][2], s_[i][3]);
        }
        __syncthreads();

        // O += P @ V : thread cols tx*4..+3
        for (int s4 = 0; s4 < 16; s4++) {
            float4 v4[4];
            for (int js = 0; js < 4; js++) v4[js] = *(float4*)&Vs[s4 * 4 + js][tx * 4];
            for (int i = 0; i < 4; i++) {
                const float4 p4 = *(float4*)&Ps[ty * 4 + i][s4 * 4];
                o_[i][0] += p4.x * v4[0].x + p4.y * v4[1].x + p4.z * v4[2].x + p4.w * v4[3].x;
                o_[i][1] += p4.x * v4[0].y + p4.y * v4[1].y + p4.z * v4[2].y + p4.w * v4[3].y;
                o_[i][2] += p4.x * v4[0].z + p4.y * v4[1].z + p4.z * v4[2].z + p4.w * v4[3].z;
                o_[i][3] += p4.x * v4[0].w + p4.y * v4[1].w + p4.z * v4[2].w + p4.w * v4[3].w;
            }
        }
    }

    for (int i = 0; i < 4; i++) {
        const float inv = 1.0f / l_i[i];
        const size_t rowoff = base + (size_t)(q0 + ty * 4 + i) * 1024 + tx * 4;
        for (int j = 0; j < 4; j++) ctx[rowoff + j] = f2b(o_[i][j] * inv);
    }
}

// ---------------- launcher ----------------
extern "C" void kernel_launch(void* const* d_in, const int* in_sizes, int n_in,
                              void* d_out, int out_size, void* d_ws, size_t ws_size,
                              hipStream_t stream) {
    const float* x   = (const float*)d_in[0];
    const float* Wq  = (const float*)d_in[1];
    const float* bq  = (const float*)d_in[2];
    const float* Wk  = (const float*)d_in[3];
    const float* bk  = (const float*)d_in[4];
    const float* Wv  = (const float*)d_in[5];
    const float* bv  = (const float*)d_in[6];
    const float* Wo  = (const float*)d_in[7];
    const float* bo  = (const float*)d_in[8];
    const float* W1  = (const float*)d_in[9];
    const float* b1  = (const float*)d_in[10];
    const float* W2  = (const float*)d_in[11];
    const float* b2  = (const float*)d_in[12];
    const float* g1  = (const float*)d_in[13];
    const float* be1 = (const float*)d_in[14];
    const float* g2  = (const float*)d_in[15];
    const float* be2 = (const float*)d_in[16];
    float* out = (float*)d_out;

    const size_t MB = 1ull << 20;
    char* ws = (char*)d_ws;
    // layout (232 MB total):
    float* h_f   = (float*)(ws + 0);          // 32MB, live until Wo residual
    u16*   h_b   = (u16*)(ws + 32 * MB);      // 16MB, reused as ctx_b after QKV
    float* q_f   = (float*)(ws + 48 * MB);    // 32MB
    float* k_f   = (float*)(ws + 80 * MB);    // 32MB
    float* v_f   = (float*)(ws + 112 * MB);   // 32MB
    float* hres  = (float*)(ws + 144 * MB);   // 32MB, LN2 in-place -> h2 fp32
    u16*   h2_b  = (u16*)(ws + 176 * MB);     // 16MB
    u16*   g_b   = (u16*)(ws + 48 * MB);      // 64MB, overlaps dead q_f/k_f
    u16*   wq_t  = (u16*)(ws + 192 * MB);     // 2MB each
    u16*   wk_t  = (u16*)(ws + 194 * MB);
    u16*   wv_t  = (u16*)(ws + 196 * MB);
    u16*   wo_t  = (u16*)(ws + 198 * MB);
    u16*   w1_t  = (u16*)(ws + 200 * MB);     // 8MB (4096x1024)
    u16*   w2_t  = (u16*)(ws + 208 * MB);     // 8MB (1024x4096)
    u16*   ctx_b = h_b;

    const int M = 8192, D = 1024, FF = 4096;
    const dim3 tb(32, 8);

    // weight prep: transpose + bf16
    k_tconv<<<dim3(32, 32), tb, 0, stream>>>(Wq, wq_t, D, D);
    k_tconv<<<dim3(32, 32), tb, 0, stream>>>(Wk, wk_t, D, D);
    k_tconv<<<dim3(32, 32), tb, 0, stream>>>(Wv, wv_t, D, D);
    k_tconv<<<dim3(32, 32), tb, 0, stream>>>(Wo, wo_t, D, D);
    k_tconv<<<dim3(128, 32), tb, 0, stream>>>(W1, w1_t, D, FF);
    k_tconv<<<dim3(32, 128), tb, 0, stream>>>(W2, w2_t, FF, D);

    // LN1: x -> h (fp32 + bf16)
    k_ln<<<M, 256, 0, stream>>>(x, g1, be1, h_f, h_b);

    // QKV GEMMs (fp32 out for attention)
    k_gemm<false, false, true, false><<<dim3(8, 64), 256, 0, stream>>>(h_b, wq_t, bq, nullptr, q_f, nullptr, M, D, D);
    k_gemm<false, false, true, false><<<dim3(8, 64), 256, 0, stream>>>(h_b, wk_t, bk, nullptr, k_f, nullptr, M, D, D);
    k_gemm<false, false, true, false><<<dim3(8, 64), 256, 0, stream>>>(h_b, wv_t, bv, nullptr, v_f, nullptr, M, D, D);

    // attention -> ctx bf16
    k_attn<<<2048, 256, 0, stream>>>(q_f, k_f, v_f, ctx_b);

    // Wo + residual(h) -> hres fp32
    k_gemm<false, true, true, false><<<dim3(8, 64), 256, 0, stream>>>(ctx_b, wo_t, bo, h_f, hres, nullptr, M, D, D);

    // LN2 (in-place fp32 + bf16)
    k_ln<<<M, 256, 0, stream>>>(hres, g2, be2, hres, h2_b);

    // FFN1 + exact GELU -> g bf16
    k_gemm<true, false, false, true><<<dim3(32, 64), 256, 0, stream>>>(h2_b, w1_t, b1, nullptr, nullptr, g_b, M, FF, D);

    // FFN2 + residual(h2) -> out fp32
    k_gemm<false, true, true, false><<<dim3(8, 64), 256, 0, stream>>>(g_b, w2_t, b2, hres, out, nullptr, M, D, FF);
}

// Round 2
// 1259.294 us; speedup vs baseline: 1.5901x; 1.5901x over previous
//
#include <hip/hip_runtime.h>
#include <hip/hip_bf16.h>

// ---------------- common helpers ----------------
typedef unsigned short u16;
typedef __attribute__((ext_vector_type(8))) short bf16x8;
typedef __attribute__((ext_vector_type(4))) float floatx4;

__device__ __forceinline__ u16 f2b(float f) {
    union { float f; unsigned int u; } a; a.f = f;
    unsigned int u = a.u;
    // round-to-nearest-even bf16
    unsigned int r = (u + 0x7fffu + ((u >> 16) & 1u)) >> 16;
    return (u16)r;
}

// ---------------- LayerNorm (ddof=1), writes fp32 + bf16 ----------------
__global__ __launch_bounds__(256) void k_ln(const float* __restrict__ x,
                                            const float* __restrict__ g,
                                            const float* __restrict__ be,
                                            float* __restrict__ yf,
                                            u16* __restrict__ yb) {
    const int row = blockIdx.x;
    const int t = threadIdx.x;
    const float4 xv = ((const float4*)(x + (size_t)row * 1024))[t];
    float s  = xv.x + xv.y + xv.z + xv.w;
    float ss = xv.x * xv.x + xv.y * xv.y + xv.z * xv.z + xv.w * xv.w;
    for (int m = 1; m < 64; m <<= 1) {
        s  += __shfl_xor(s, m);
        ss += __shfl_xor(ss, m);
    }
    __shared__ float sm[8];
    const int wave = t >> 6, lane = t & 63;
    if (lane == 0) { sm[wave] = s; sm[4 + wave] = ss; }
    __syncthreads();
    s  = sm[0] + sm[1] + sm[2] + sm[3];
    ss = sm[4] + sm[5] + sm[6] + sm[7];
    const float mean = s * (1.0f / 1024.0f);
    const float var  = (ss - 1024.0f * mean * mean) * (1.0f / 1023.0f); // ddof=1
    const float rstd = rsqrtf(var + 1e-5f);
    const float4 gv = ((const float4*)g)[t];
    const float4 bv = ((const float4*)be)[t];
    float4 y;
    y.x = (xv.x - mean) * rstd * gv.x + bv.x;
    y.y = (xv.y - mean) * rstd * gv.y + bv.y;
    y.z = (xv.z - mean) * rstd * gv.z + bv.z;
    y.w = (xv.w - mean) * rstd * gv.w + bv.w;
    ((float4*)(yf + (size_t)row * 1024))[t] = y;
    uint2 pk;
    pk.x = (unsigned int)f2b(y.x) | ((unsigned int)f2b(y.y) << 16);
    pk.y = (unsigned int)f2b(y.z) | ((unsigned int)f2b(y.w) << 16);
    *(uint2*)(yb + (size_t)row * 1024 + t * 4) = pk;
}

// ---------------- weight transpose + convert: W(KxN) fp32 -> Wt(NxK) bf16 ----------------
__global__ __launch_bounds__(256) void k_tconv(const float* __restrict__ W,
                                               u16* __restrict__ Wt,
                                               int K, int N) {
    __shared__ float tile[32][33];
    const int n0 = blockIdx.x * 32, k0 = blockIdx.y * 32;
    const int tx = threadIdx.x, ty = threadIdx.y; // 32 x 8
    for (int i = 0; i < 4; i++) {
        const int kr = ty + i * 8;
        tile[kr][tx] = W[(size_t)(k0 + kr) * N + n0 + tx];
    }
    __syncthreads();
    for (int i = 0; i < 4; i++) {
        const int nr = ty + i * 8;
        Wt[(size_t)(n0 + nr) * K + k0 + tx] = f2b(tile[tx][nr]);
    }
}

// ---------------- bf16 MFMA GEMM: C = A(MxK) @ Bt(NxK)^T + bias ----------------
// 128x128 tile, BK=32, 256 threads (4 waves, each 64x64 = 4x4 frags of 16x16x32)
// VT: write bf16 output in per-head transposed layout vt[b][h][d][t] (N must be 1024)
template <bool GELU, bool RESID, bool WF32, bool WBF16, bool VT = false>
__global__ __launch_bounds__(256) void k_gemm(const u16* __restrict__ A,
                                              const u16* __restrict__ Bt,
                                              const float* __restrict__ bias,
                                              const float* __restrict__ resid,
                                              float* __restrict__ outF,
                                              u16* __restrict__ outB,
                                              int M, int N, int K) {
    __shared__ u16 As[128 * 32];
    __shared__ u16 Bs[128 * 32];
    const int t = threadIdx.x;
    const int m0 = blockIdx.y * 128, n0 = blockIdx.x * 128;
    const int lane = t & 63, wave = t >> 6;
    const int wm = (wave >> 1) * 64, wn = (wave & 1) * 64;
    const int r16 = lane & 15, quad = lane >> 4;

    floatx4 acc[4][4];
    const floatx4 zero = {0.0f, 0.0f, 0.0f, 0.0f};
    for (int i = 0; i < 4; i++)
        for (int j = 0; j < 4; j++) acc[i][j] = zero;

    const int c0 = t, c1 = t + 256;
    const int r0 = c0 >> 2, f0 = c0 & 3;
    const int r1 = c1 >> 2, f1 = c1 & 3;

    for (int kk = 0; kk < K; kk += 32) {
        const uint4 va0 = *(const uint4*)(A  + (size_t)(m0 + r0) * K + kk + f0 * 8);
        const uint4 vb0 = *(const uint4*)(Bt + (size_t)(n0 + r0) * K + kk + f0 * 8);
        const uint4 va1 = *(const uint4*)(A  + (size_t)(m0 + r1) * K + kk + f1 * 8);
        const uint4 vb1 = *(const uint4*)(Bt + (size_t)(n0 + r1) * K + kk + f1 * 8);
        *(uint4*)(As + r0 * 32 + f0 * 8) = va0;
        *(uint4*)(Bs + r0 * 32 + f0 * 8) = vb0;
        *(uint4*)(As + r1 * 32 + f1 * 8) = va1;
        *(uint4*)(Bs + r1 * 32 + f1 * 8) = vb1;
        __syncthreads();

        bf16x8 af[4], bfr[4];
        for (int i = 0; i < 4; i++)
            af[i] = *(const bf16x8*)(As + (wm + i * 16 + r16) * 32 + quad * 8);
        for (int i = 0; i < 4; i++)
            bfr[i] = *(const bf16x8*)(Bs + (wn + i * 16 + r16) * 32 + quad * 8);
        for (int mi = 0; mi < 4; mi++)
            for (int ni = 0; ni < 4; ni++)
                acc[mi][ni] = __builtin_amdgcn_mfma_f32_16x16x32_bf16(af[mi], bfr[ni], acc[mi][ni], 0, 0, 0);
        __syncthreads();
    }

    // epilogue: C/D layout col = lane&15, row = quad*4 + reg
    for (int mi = 0; mi < 4; mi++)
        for (int ni = 0; ni < 4; ni++) {
            const int gcol = n0 + wn + ni * 16 + r16;
            const float bv = bias[gcol];
            if (VT) {
                // vt[b][h][d][t], 4 consecutive t rows -> one 8B store
                const int grow0 = m0 + wm + mi * 16 + quad * 4;
                const int bb = grow0 >> 10, t0 = grow0 & 1023;
                const int hh = gcol >> 6, dd = gcol & 63;
                ushort4 pk;
                pk.x = f2b(acc[mi][ni][0] + bv);
                pk.y = f2b(acc[mi][ni][1] + bv);
                pk.z = f2b(acc[mi][ni][2] + bv);
                pk.w = f2b(acc[mi][ni][3] + bv);
                *(ushort4*)(outB + ((size_t)(bb * 16 + hh) * 64 + dd) * 1024 + t0) = pk;
            } else {
                for (int r = 0; r < 4; r++) {
                    const int grow = m0 + wm + mi * 16 + quad * 4 + r;
                    float v = acc[mi][ni][r] + bv;
                    if (GELU) v = 0.5f * v * (1.0f + erff(v * 0.70710678118654752f));
                    const size_t o = (size_t)grow * N + gcol;
                    if (RESID) v += resid[o];
                    if (WF32) outF[o] = v;
                    if (WBF16) outB[o] = f2b(v);
                }
            }
        }
}

// ---------------- bf16 MFMA flash attention ----------------
// grid: B*H*(T/64)=2048 blocks x 256 threads. Block = one (b,h), 64 q rows.
// 4 waves, each owns 16 q rows. K/V tiles of 64 keys, 16 iterations.
// q,k: bf16 [b*T][1024] (head h at cols h*64..). vt: bf16 [b][h][64][1024].
__global__ __launch_bounds__(256) void k_attn_mfma(const u16* __restrict__ q,
                                                   const u16* __restrict__ k,
                                                   const u16* __restrict__ vt,
                                                   u16* __restrict__ ctx) {
    // panel-split tiles: [panel][row][32] u16, row stride 64B (m97 pattern)
    __shared__ u16 Qs[2][64][32];
    __shared__ u16 Ks[2][64][32];
    __shared__ u16 Vs[2][64][32]; // Vs[p][d][s'], s = p*32+s'
    __shared__ u16 Ps[2][64][32]; // Ps[p][qrow][s']
    const int t = threadIdx.x;
    const int lane = t & 63, wave = t >> 6;
    const int r16 = lane & 15, quad = lane >> 4;
    const int wq = wave * 16;
    const int bx = blockIdx.x;
    const int qt = bx & 15, hh = (bx >> 4) & 15, bb = bx >> 8;
    const size_t qk_base = ((size_t)bb * 1024) * 1024 + hh * 64;
    const size_t vt_base = ((size_t)(bb * 16 + hh) * 64) * 1024;
    const int q0 = qt * 64;

    // stage Q: thread -> row = t>>2, 16-elem chunk ch = t&3 (32B = 2 x uint4)
    const int srow = t >> 2, ch = t & 3;
    const int pnl = ch >> 1, soff = (ch & 1) * 16;
    {
        const u16* gp = q + qk_base + (size_t)(q0 + srow) * 1024 + ch * 16;
        *(uint4*)&Qs[pnl][srow][soff]     = *(const uint4*)gp;
        *(uint4*)&Qs[pnl][srow][soff + 8] = *(const uint4*)(gp + 8);
    }

    float m_i[4], l_i[4];
    floatx4 acc_o[4];
    const floatx4 zero = {0.0f, 0.0f, 0.0f, 0.0f};
    for (int r = 0; r < 4; r++) { m_i[r] = -INFINITY; l_i[r] = 0.0f; }
    for (int ni = 0; ni < 4; ni++) acc_o[ni] = zero;

    for (int st = 0; st < 16; st++) {
        __syncthreads(); // prev-iter PV reads done before restage
        const int s0 = st * 64;
        {
            const u16* gk = k + qk_base + (size_t)(s0 + srow) * 1024 + ch * 16;
            *(uint4*)&Ks[pnl][srow][soff]     = *(const uint4*)gk;
            *(uint4*)&Ks[pnl][srow][soff + 8] = *(const uint4*)(gk + 8);
            const u16* gv = vt + vt_base + (size_t)srow * 1024 + s0 + ch * 16;
            *(uint4*)&Vs[pnl][srow][soff]     = *(const uint4*)gv;
            *(uint4*)&Vs[pnl][srow][soff + 8] = *(const uint4*)(gv + 8);
        }
        __syncthreads();

        // S = Q K^T (wave's 16 q rows x 64 keys)
        floatx4 accs[4];
        for (int ni = 0; ni < 4; ni++) accs[ni] = zero;
        for (int ks = 0; ks < 2; ks++) {
            const bf16x8 af = *(const bf16x8*)&Qs[ks][wq + r16][quad * 8];
            for (int ni = 0; ni < 4; ni++) {
                const bf16x8 bf = *(const bf16x8*)&Ks[ks][ni * 16 + r16][quad * 8];
                accs[ni] = __builtin_amdgcn_mfma_f32_16x16x32_bf16(af, bf, accs[ni], 0, 0, 0);
            }
        }

        // online softmax; C layout: row = quad*4+r, col = ni*16+r16
        for (int r = 0; r < 4; r++) {
            float sv[4];
            float mx = -INFINITY;
            for (int ni = 0; ni < 4; ni++) {
                sv[ni] = accs[ni][r] * 0.125f;
                mx = fmaxf(mx, sv[ni]);
            }
            for (int m = 1; m < 16; m <<= 1) mx = fmaxf(mx, __shfl_xor(mx, m));
            const float mn = fmaxf(m_i[r], mx);
            const float al = __expf(m_i[r] - mn);
            float ps = 0.0f;
            u16 pb[4];
            for (int ni = 0; ni < 4; ni++) {
                const float p = __expf(sv[ni] - mn);
                ps += p;
                pb[ni] = f2b(p);
            }
            for (int m = 1; m < 16; m <<= 1) ps += __shfl_xor(ps, m);
            l_i[r] = l_i[r] * al + ps;
            m_i[r] = mn;
            for (int ni = 0; ni < 4; ni++) acc_o[ni][r] *= al;
            const int prow = wq + quad * 4 + r;
            for (int ni = 0; ni < 4; ni++)
                Ps[ni >> 1][prow][(ni & 1) * 16 + r16] = pb[ni];
        }
        // P written & read by the same wave (rows wq..wq+15) -> no barrier needed

        // O += P @ V : A = P rows (wq+r16), B = Vt rows (d = ni*16+r16)
        for (int ks = 0; ks < 2; ks++) {
            const bf16x8 af = *(const bf16x8*)&Ps[ks][wq + r16][quad * 8];
            for (int ni = 0; ni < 4; ni++) {
                const bf16x8 bf = *(const bf16x8*)&Vs[ks][ni * 16 + r16][quad * 8];
                acc_o[ni] = __builtin_amdgcn_mfma_f32_16x16x32_bf16(af, bf, acc_o[ni], 0, 0, 0);
            }
        }
    }

    // normalize + write ctx bf16 [b*T][1024]
    for (int r = 0; r < 4; r++) {
        const float inv = 1.0f / l_i[r];
        const size_t rowoff = qk_base + (size_t)(q0 + wq + quad * 4 + r) * 1024;
        for (int ni = 0; ni < 4; ni++)
            ctx[rowoff + ni * 16 + r16] = f2b(acc_o[ni][r] * inv);
    }
}

// ---------------- launcher ----------------
extern "C" void kernel_launch(void* const* d_in, const int* in_sizes, int n_in,
                              void* d_out, int out_size, void* d_ws, size_t ws_size,
                              hipStream_t stream) {
    const float* x   = (const float*)d_in[0];
    const float* Wq  = (const float*)d_in[1];
    const float* bq  = (const float*)d_in[2];
    const float* Wk  = (const float*)d_in[3];
    const float* bk  = (const float*)d_in[4];
    const float* Wv  = (const float*)d_in[5];
    const float* bv  = (const float*)d_in[6];
    const float* Wo  = (const float*)d_in[7];
    const float* bo  = (const float*)d_in[8];
    const float* W1  = (const float*)d_in[9];
    const float* b1  = (const float*)d_in[10];
    const float* W2  = (const float*)d_in[11];
    const float* b2  = (const float*)d_in[12];
    const float* g1  = (const float*)d_in[13];
    const float* be1 = (const float*)d_in[14];
    const float* g2  = (const float*)d_in[15];
    const float* be2 = (const float*)d_in[16];
    float* out = (float*)d_out;

    const size_t MB = 1ull << 20;
    char* ws = (char*)d_ws;
    // layout (224 MB):
    float* h_f   = (float*)(ws + 0);          // 32MB fp32 h (live to Wo resid)
    u16*   h_b   = (u16*)(ws + 32 * MB);      // 16MB bf16 h; reused as ctx after QKV
    u16*   q_b   = (u16*)(ws + 48 * MB);      // 16MB
    u16*   k_b   = (u16*)(ws + 64 * MB);      // 16MB
    u16*   vt_b  = (u16*)(ws + 80 * MB);      // 16MB (per-head transposed)
    float* hres  = (float*)(ws + 96 * MB);    // 32MB, LN2 in-place
    u16*   h2_b  = (u16*)(ws + 128 * MB);     // 16MB
    u16*   g_b   = (u16*)(ws + 144 * MB);     // 64MB gelu acts
    u16*   wq_t  = (u16*)(ws + 208 * MB);     // 2MB each
    u16*   wk_t  = (u16*)(ws + 210 * MB);
    u16*   wv_t  = (u16*)(ws + 212 * MB);
    u16*   wo_t  = (u16*)(ws + 214 * MB);
    u16*   w1_t  = (u16*)(ws + 216 * MB);     // 8MB
    u16*   w2_t  = (u16*)(ws + 224 * MB - 8 * MB + 0); // reuse tail: 8MB at 224-8
    // (keep inside 232MB: w1_t 216..224, w2_t 224..232 would exceed 224; use 216+8)
    w2_t = (u16*)(ws + 200 * MB);             // 8MB at 200..208 (g_b ends at 208? no, 144+64=208)
    // fix: place w2_t after wo_t region instead
    w1_t = (u16*)(ws + 216 * MB);             // 216..224
    w2_t = (u16*)(ws + 224 * MB);             // 224..232
    u16* ctx_b = h_b;

    const int M = 8192, D = 1024, FF = 4096;
    const dim3 tb(32, 8);

    // weight prep
    k_tconv<<<dim3(32, 32), tb, 0, stream>>>(Wq, wq_t, D, D);
    k_tconv<<<dim3(32, 32), tb, 0, stream>>>(Wk, wk_t, D, D);
    k_tconv<<<dim3(32, 32), tb, 0, stream>>>(Wv, wv_t, D, D);
    k_tconv<<<dim3(32, 32), tb, 0, stream>>>(Wo, wo_t, D, D);
    k_tconv<<<dim3(128, 32), tb, 0, stream>>>(W1, w1_t, D, FF);
    k_tconv<<<dim3(32, 128), tb, 0, stream>>>(W2, w2_t, FF, D);

    // LN1
    k_ln<<<M, 256, 0, stream>>>(x, g1, be1, h_f, h_b);

    // QKV GEMMs -> bf16 (V in per-head transposed layout)
    k_gemm<false, false, false, true><<<dim3(8, 64), 256, 0, stream>>>(h_b, wq_t, bq, nullptr, nullptr, q_b, M, D, D);
    k_gemm<false, false, false, true><<<dim3(8, 64), 256, 0, stream>>>(h_b, wk_t, bk, nullptr, nullptr, k_b, M, D, D);
    k_gemm<false, false, false, true, true><<<dim3(8, 64), 256, 0, stream>>>(h_b, wv_t, bv, nullptr, nullptr, vt_b, M, D, D);

    // MFMA flash attention -> ctx bf16
    k_attn_mfma<<<2048, 256, 0, stream>>>(q_b, k_b, vt_b, ctx_b);

    // Wo + residual(h)
    k_gemm<false, true, true, false><<<dim3(8, 64), 256, 0, stream>>>(ctx_b, wo_t, bo, h_f, hres, nullptr, M, D, D);

    // LN2 (in-place fp32 + bf16)
    k_ln<<<M, 256, 0, stream>>>(hres, g2, be2, hres, h2_b);

    // FFN1 + exact GELU
    k_gemm<true, false, false, true><<<dim3(32, 64), 256, 0, stream>>>(h2_b, w1_t, b1, nullptr, nullptr, g_b, M, FF, D);

    // FFN2 + residual(h2)
    k_gemm<false, true, true, false><<<dim3(8, 64), 256, 0, stream>>>(g_b, w2_t, b2, hres, out, nullptr, M, D, FF);
}